// Round 1
// baseline (26846.732 us; speedup 1.0000x reference)
//
#include <hip/hip_runtime.h>
#include <math.h>

#define RAWF 92
#define CF 64
#define NBRF 41
#define NBRP 44
#define MN 24
#define HD 128

__device__ __forceinline__ void lds_fence() {
  asm volatile("s_waitcnt lgkmcnt(0)" ::: "memory");
  __builtin_amdgcn_wave_barrier();
}

__device__ __forceinline__ float wsum64(float v) {
#pragma unroll
  for (int m = 32; m >= 1; m >>= 1) v += __shfl_xor(v, m, 64);
  return v;
}

__device__ __forceinline__ float sigm(float x) { return 1.f / (1.f + __expf(-x)); }
__device__ __forceinline__ float sftp(float x) { return x > 20.f ? x : __logf(1.f + __expf(x)); }

// ---------------------------------------------------------------- embed
__global__ __launch_bounds__(256) void k_embed(
    const float* __restrict__ af, const float* __restrict__ Wemb,
    const float* __restrict__ bemb, float* __restrict__ h, int nAtoms) {
  __shared__ float Ws[96 * 64];      // padded to 96 rows, pad rows = 0
  __shared__ float rows[4][96];
  int tid = threadIdx.x;
  for (int t = tid; t < 96 * 64; t += 256) {
    int r = t >> 6;
    Ws[t] = (r < RAWF) ? Wemb[t] : 0.f;
  }
  __syncthreads();
  int w = tid >> 6, j = tid & 63;
  float bj = bemb[j];
  int wg = (blockIdx.x << 2) + w, nw = gridDim.x << 2;
  for (int n = wg; n < nAtoms; n += nw) {
    const float* ar = af + (size_t)n * RAWF;
    rows[w][j] = ar[j];
    if (j < 32) rows[w][64 + j] = (64 + j < RAWF) ? ar[64 + j] : 0.f;
    lds_fence();
    float acc = bj;
#pragma unroll
    for (int kk = 0; kk < 24; ++kk) {
      float4 q = *reinterpret_cast<const float4*>(&rows[w][kk * 4]);
      const float* base = &Ws[(kk * 4) * 64 + j];
      acc += q.x * base[0] + q.y * base[64] + q.z * base[128] + q.w * base[192];
    }
    h[(size_t)n * 64 + j] = acc;
    lds_fence();
  }
}

// ---------------------------------------------------------------- LN + phi_c
__global__ __launch_bounds__(256) void k_ln_phic(
    const float* __restrict__ h, const float* __restrict__ lns,
    const float* __restrict__ lnb, const float* __restrict__ Wc,
    const float* __restrict__ bc, float* __restrict__ x, float* __restrict__ pc,
    int nAtoms) {
  __shared__ float Ws[64 * 64];
  __shared__ float rows[4][64];
  int tid = threadIdx.x;
  for (int t = tid; t < 1024; t += 256)
    reinterpret_cast<float4*>(Ws)[t] = reinterpret_cast<const float4*>(Wc)[t];
  __syncthreads();
  int w = tid >> 6, j = tid & 63;
  float sj = lns[j], bj = lnb[j], bcj = bc[j];
  int wg = (blockIdx.x << 2) + w, nw = gridDim.x << 2;
  for (int n = wg; n < nAtoms; n += nw) {
    float hv = h[(size_t)n * 64 + j];
    float mu = wsum64(hv) * (1.f / 64.f);
    float d = hv - mu;
    float var = wsum64(d * d) * (1.f / 64.f);
    float xv = d * rsqrtf(var + 1e-6f) * sj + bj;
    x[(size_t)n * 64 + j] = xv;
    rows[w][j] = xv;
    lds_fence();
    float acc = bcj;
#pragma unroll
    for (int kk = 0; kk < 16; ++kk) {
      float4 q = *reinterpret_cast<const float4*>(&rows[w][kk * 4]);
      const float* base = &Ws[(kk * 4) * 64 + j];
      acc += q.x * base[0] + q.y * base[64] + q.z * base[128] + q.w * base[192];
    }
    pc[(size_t)n * 64 + j] = acc;
    lds_fence();
  }
}

// ---------------------------------------------------------------- conv (the hot one)
__global__ __launch_bounds__(256) void k_conv(
    const float* __restrict__ x, const float* __restrict__ pc,
    const float* __restrict__ nbrf, const int* __restrict__ idx,
    const float* __restrict__ Wn, const float* __restrict__ bn,
    const float* __restrict__ We, const float* __restrict__ be,
    const float* __restrict__ Wg, const float* __restrict__ bg,
    const float* __restrict__ Wm, const float* __restrict__ bm,
    float* __restrict__ h, int nAtoms) {
  __shared__ float WnS[64 * 64];
  __shared__ float WeS[NBRP * 64];   // padded rows 41..43 = 0
  __shared__ float WgS[64 * 64];
  __shared__ float WmS[64 * 64];
  __shared__ float Xs[4][8 * 64];    // gathered x rows, reused for inter
  __shared__ float Es[4][8 * NBRP];  // nbr_fea rows (padded to 44)
  int tid = threadIdx.x;
  for (int t = tid; t < 1024; t += 256) {
    reinterpret_cast<float4*>(WnS)[t] = reinterpret_cast<const float4*>(Wn)[t];
    reinterpret_cast<float4*>(WgS)[t] = reinterpret_cast<const float4*>(Wg)[t];
    reinterpret_cast<float4*>(WmS)[t] = reinterpret_cast<const float4*>(Wm)[t];
  }
  for (int t = tid; t < NBRP * 16; t += 256) {  // 704 float4
    reinterpret_cast<float4*>(WeS)[t] =
        (t < NBRF * 16) ? reinterpret_cast<const float4*>(We)[t]
                        : make_float4(0.f, 0.f, 0.f, 0.f);
  }
  __syncthreads();
  int w = tid >> 6, j = tid & 63;
  float bnj = bn[j], bej = be[j], bgj = bg[j], bmj = bm[j];
  float* Xw = Xs[w];
  float* Ew = Es[w];
  int wg = (blockIdx.x << 2) + w, nw = gridDim.x << 2;
  for (int n = wg; n < nAtoms; n += nw) {
    float pcj = pc[(size_t)n * 64 + j];
    int myidx = (j < MN) ? idx[(size_t)n * MN + j] : 0;
    float accj = 0.f;
#pragma unroll
    for (int cch = 0; cch < 3; ++cch) {
      lds_fence();  // prior-chunk reads complete before overwrite
#pragma unroll
      for (int m = 0; m < 8; ++m) {
        int nb = __shfl(myidx, cch * 8 + m, 64);
        Xw[m * 64 + j] = x[(size_t)nb * 64 + j];
        if (j < NBRP)
          Ew[m * NBRP + j] =
              (j < NBRF) ? nbrf[((size_t)n * MN + cch * 8 + m) * NBRF + j] : 0.f;
      }
      lds_fence();
      float pn[8], pe[8];
#pragma unroll
      for (int m = 0; m < 8; ++m) { pn[m] = bnj; pe[m] = bej; }
#pragma unroll
      for (int kk = 0; kk < 16; ++kk) {
        const float* base = &WnS[(kk * 4) * 64 + j];
        float w0 = base[0], w1 = base[64], w2 = base[128], w3 = base[192];
#pragma unroll
        for (int m = 0; m < 8; ++m) {
          float4 q = *reinterpret_cast<const float4*>(&Xw[m * 64 + kk * 4]);
          pn[m] += q.x * w0 + q.y * w1 + q.z * w2 + q.w * w3;
        }
      }
#pragma unroll
      for (int kk = 0; kk < 11; ++kk) {
        const float* base = &WeS[(kk * 4) * 64 + j];
        float w0 = base[0], w1 = base[64], w2 = base[128], w3 = base[192];
#pragma unroll
        for (int m = 0; m < 8; ++m) {
          float4 q = *reinterpret_cast<const float4*>(&Ew[m * NBRP + kk * 4]);
          pe[m] += q.x * w0 + q.y * w1 + q.z * w2 + q.w * w3;
        }
      }
      lds_fence();  // phi_n reads of Xw done before inter overwrite
#pragma unroll
      for (int m = 0; m < 8; ++m) Xw[m * 64 + j] = pcj * pn[m] * pe[m];
      lds_fence();
      float g8[8], s8[8];
#pragma unroll
      for (int m = 0; m < 8; ++m) { g8[m] = bgj; s8[m] = bmj; }
#pragma unroll
      for (int kk = 0; kk < 16; ++kk) {
        const float* gb = &WgS[(kk * 4) * 64 + j];
        const float* mb = &WmS[(kk * 4) * 64 + j];
        float g0 = gb[0], g1 = gb[64], g2 = gb[128], g3 = gb[192];
        float m0 = mb[0], m1 = mb[64], m2 = mb[128], m3 = mb[192];
#pragma unroll
        for (int m = 0; m < 8; ++m) {
          float4 q = *reinterpret_cast<const float4*>(&Xw[m * 64 + kk * 4]);
          g8[m] += q.x * g0 + q.y * g1 + q.z * g2 + q.w * g3;
          s8[m] += q.x * m0 + q.y * m1 + q.z * m2 + q.w * m3;
        }
      }
#pragma unroll
      for (int m = 0; m < 8; ++m) accj += sigm(g8[m]) * sftp(s8[m]);
    }
    h[(size_t)n * 64 + j] += accj;
  }
}

// ---------------------------------------------------------------- readout
__global__ __launch_bounds__(256) void k_readout(
    const float* __restrict__ h, const float* __restrict__ Wr1,
    const float* __restrict__ br1, const float* __restrict__ Wr2,
    const float* __restrict__ br2, const float* __restrict__ Wr3,
    const float* __restrict__ br3, float* __restrict__ partials, int nAtoms) {
  __shared__ float W1[64 * 128];
  __shared__ float W2[128 * 64];
  __shared__ float w3s[64];
  __shared__ float rowbuf[4][128];
  __shared__ float wsum[4];
  int tid = threadIdx.x;
  for (int t = tid; t < 2048; t += 256) {
    reinterpret_cast<float4*>(W1)[t] = reinterpret_cast<const float4*>(Wr1)[t];
    reinterpret_cast<float4*>(W2)[t] = reinterpret_cast<const float4*>(Wr2)[t];
  }
  if (tid < 64) w3s[tid] = Wr3[tid];
  __syncthreads();
  int w = tid >> 6, j = tid & 63;
  float b1a = br1[j], b1b = br1[64 + j], b2 = br2[j];
  float w3 = w3s[j], br3v = br3[0];
  float lsum = 0.f;
  int wg = (blockIdx.x << 2) + w, nw = gridDim.x << 2;
  for (int n = wg; n < nAtoms; n += nw) {
    lds_fence();
    rowbuf[w][j] = h[(size_t)n * 64 + j];
    lds_fence();
    float a0 = b1a, a1 = b1b;
#pragma unroll
    for (int kk = 0; kk < 16; ++kk) {
      float4 q = *reinterpret_cast<const float4*>(&rowbuf[w][kk * 4]);
      const float* base = &W1[(kk * 4) * 128 + j];
      a0 += q.x * base[0] + q.y * base[128] + q.z * base[256] + q.w * base[384];
      a1 += q.x * base[64] + q.y * base[192] + q.z * base[320] + q.w * base[448];
    }
    a0 = sftp(a0);
    a1 = sftp(a1);
    lds_fence();
    rowbuf[w][j] = a0;
    rowbuf[w][64 + j] = a1;
    lds_fence();
    float a2 = b2;
#pragma unroll
    for (int kk = 0; kk < 32; ++kk) {
      float4 q = *reinterpret_cast<const float4*>(&rowbuf[w][kk * 4]);
      const float* base = &W2[(kk * 4) * 64 + j];
      a2 += q.x * base[0] + q.y * base[64] + q.z * base[128] + q.w * base[192];
    }
    a2 = sftp(a2);
    float site = wsum64(a2 * w3) + br3v;
    if (j == 0) lsum += site;
  }
  if (j == 0) wsum[w] = lsum;
  __syncthreads();
  if (tid == 0)
    partials[blockIdx.x] = wsum[0] + wsum[1] + wsum[2] + wsum[3];
}

__global__ __launch_bounds__(256) void k_final(const float* __restrict__ partials,
                                               int nparts, float* __restrict__ out,
                                               float invN) {
  __shared__ float s[256];
  float v = 0.f;
  for (int t = threadIdx.x; t < nparts; t += 256) v += partials[t];
  s[threadIdx.x] = v;
  __syncthreads();
  for (int off = 128; off > 0; off >>= 1) {
    if (threadIdx.x < off) s[threadIdx.x] += s[threadIdx.x + off];
    __syncthreads();
  }
  if (threadIdx.x == 0) out[0] = s[0] * invN;
}

// ---------------------------------------------------------------- launch
extern "C" void kernel_launch(void* const* d_in, const int* in_sizes, int n_in,
                              void* d_out, int out_size, void* d_ws, size_t ws_size,
                              hipStream_t stream) {
  const float* af   = (const float*)d_in[0];
  const float* nbrf = (const float*)d_in[1];
  const int*   idx  = (const int*)d_in[2];
  const float* Wemb = (const float*)d_in[3];
  const float* bemb = (const float*)d_in[4];
  const float* ln_s = (const float*)d_in[5];
  const float* ln_b = (const float*)d_in[6];
  const float* Wc   = (const float*)d_in[7];
  const float* bc   = (const float*)d_in[8];
  const float* Wn   = (const float*)d_in[9];
  const float* bn   = (const float*)d_in[10];
  const float* We   = (const float*)d_in[11];
  const float* be   = (const float*)d_in[12];
  const float* Wg   = (const float*)d_in[13];
  const float* bg   = (const float*)d_in[14];
  const float* Wm   = (const float*)d_in[15];
  const float* bm   = (const float*)d_in[16];
  const float* Wr1  = (const float*)d_in[17];
  const float* br1  = (const float*)d_in[18];
  const float* Wr2  = (const float*)d_in[19];
  const float* br2  = (const float*)d_in[20];
  const float* Wr3  = (const float*)d_in[21];
  const float* br3  = (const float*)d_in[22];

  int N = in_sizes[0] / RAWF;  // 50000
  float* ws = (float*)d_ws;
  size_t nc = (size_t)N * CF;
  float* h  = ws;
  float* x  = ws + nc;
  float* pcb = ws + 2 * nc;
  float* partials = ws + 3 * nc;
  const int RO_GRID = 512;

  k_embed<<<1024, 256, 0, stream>>>(af, Wemb, bemb, h, N);
  for (int i = 0; i < 3; ++i) {
    k_ln_phic<<<1024, 256, 0, stream>>>(h, ln_s + i * 64, ln_b + i * 64,
                                        Wc + i * 4096, bc + i * 64, x, pcb, N);
    k_conv<<<2048, 256, 0, stream>>>(x, pcb, nbrf, idx,
                                     Wn + i * 4096, bn + i * 64,
                                     We + i * NBRF * 64, be + i * 64,
                                     Wg + i * 4096, bg + i * 64,
                                     Wm + i * 4096, bm + i * 64, h, N);
  }
  k_readout<<<RO_GRID, 256, 0, stream>>>(h, Wr1, br1, Wr2, br2, Wr3, br3,
                                         partials, N);
  k_final<<<1, 256, 0, stream>>>(partials, RO_GRID, (float*)d_out, 1.f / N);
}

// Round 2
// 913.258 us; speedup vs baseline: 29.3967x; 29.3967x over previous
//
#include <hip/hip_runtime.h>
#include <math.h>

#define RAWF 92
#define CF 64
#define NBRF 41
#define MN 24
#define HD 128

typedef short short8 __attribute__((ext_vector_type(8)));
typedef float f32x4 __attribute__((ext_vector_type(4)));
#define MFMA_BF16 __builtin_amdgcn_mfma_f32_16x16x32_bf16

__device__ __forceinline__ void lds_fence() {
  asm volatile("s_waitcnt lgkmcnt(0)" ::: "memory");
  __builtin_amdgcn_wave_barrier();
}

__device__ __forceinline__ float wsum64(float v) {
#pragma unroll
  for (int m = 32; m >= 1; m >>= 1) v += __shfl_xor(v, m, 64);
  return v;
}

__device__ __forceinline__ float sigm(float x) { return 1.f / (1.f + __expf(-x)); }
__device__ __forceinline__ float sftp(float x) { return x > 20.f ? x : __logf(1.f + __expf(x)); }

__device__ __forceinline__ ushort f2b(float f) {  // RNE float->bf16
  unsigned u = __float_as_uint(f);
  return (ushort)((u + 0x7FFFu + ((u >> 16) & 1u)) >> 16);
}

// ------------------------------------------------ weight transpose+cast (once)
// Wt layout: [layer][mat(n,e,g,m)][n=64][k=64] bf16, We K-padded with zeros
__global__ __launch_bounds__(256) void k_prep(
    const float* __restrict__ Wn, const float* __restrict__ We,
    const float* __restrict__ Wg, const float* __restrict__ Wm,
    ushort* __restrict__ Wt) {
  int bid = blockIdx.x, layer = bid >> 2, mat = bid & 3;
  const float* src;
  int Krows = 64;
  if (mat == 0) src = Wn + layer * 4096;
  else if (mat == 1) { src = We + layer * NBRF * 64; Krows = NBRF; }
  else if (mat == 2) src = Wg + layer * 4096;
  else src = Wm + layer * 4096;
  ushort* dst = Wt + bid * 4096;
  for (int i = threadIdx.x; i < 4096; i += 256) {
    int n = i >> 6, k = i & 63;
    float v = (k < Krows) ? src[k * 64 + n] : 0.f;
    dst[n * 64 + k] = f2b(v);
  }
}

// ------------------------------------------------ fused conv via MFMA
// block = 8 atoms = 192 rows; wave w owns rows [48w,48w+48) = atoms 2w,2w+1.
// All LDS regions wave-private -> no __syncthreads needed.
__global__ __launch_bounds__(256) void k_conv_mfma(
    const float* __restrict__ x, const float* __restrict__ pcg,
    const float* __restrict__ nbrf, const int* __restrict__ idx,
    const ushort* __restrict__ Wt,  // this layer: [4][64][64] bf16 (n-major)
    const float* __restrict__ bn, const float* __restrict__ be,
    const float* __restrict__ bg, const float* __restrict__ bm,
    float* __restrict__ h, int nAtoms) {
  __shared__ ushort NbrX[192 * 72];  // gathered x (bf16), later reused as inter
  __shared__ ushort NbrF[192 * 72];  // nbr_fea (bf16), cols 41..63 zeroed
  __shared__ float pcs[8 * 64];      // phi_c rows (fp32)

  int tid = threadIdx.x;
  int w = tid >> 6, l = tid & 63, g = l >> 4, c15 = l & 15;
  int atom0 = blockIdx.x * 8;
  size_t rowg0 = (size_t)atom0 * MN;  // global row base of this block

  // ---- stage: neighbor indices for this wave's 48 rows
  int myidx = 0;
  if (l < 48) myidx = idx[rowg0 + 48 * w + l];

  // ---- stage gathered x rows -> NbrX bf16 (2 rows/iter: lanes 0-31 row r, 32-63 r+1)
  {
    float2 xv[24];
#pragma unroll
    for (int i = 0; i < 24; ++i) {
      int nb = __shfl(myidx, 2 * i + (l >> 5), 64);
      xv[i] = *reinterpret_cast<const float2*>(x + (size_t)nb * 64 + 2 * (l & 31));
    }
    unsigned* nbx32 = reinterpret_cast<unsigned*>(NbrX);
#pragma unroll
    for (int i = 0; i < 24; ++i) {
      int lr = 48 * w + 2 * i + (l >> 5);
      unsigned p = (unsigned)f2b(xv[i].x) | ((unsigned)f2b(xv[i].y) << 16);
      nbx32[lr * 36 + (l & 31)] = p;
    }
  }
  // ---- stage nbr_fea rows -> NbrF bf16 (1 row/iter, zero-pad cols 41..63)
  {
    float fv[48];
#pragma unroll
    for (int i = 0; i < 48; ++i) {
      int lr = 48 * w + i;
      fv[i] = (l < NBRF) ? nbrf[(rowg0 + lr) * NBRF + l] : 0.f;
    }
#pragma unroll
    for (int i = 0; i < 48; ++i) {
      int lr = 48 * w + i;
      NbrF[lr * 72 + l] = f2b(fv[i]);
    }
  }
  // ---- stage phi_c rows (fp32) for this wave's 2 atoms
#pragma unroll
  for (int rr = 0; rr < 2; ++rr) {
    int la = 2 * w + rr;
    pcs[la * 64 + l] = pcg[(size_t)(atom0 + la) * 64 + l];
  }

  // ---- per-lane constants
  float bnv[4], bev[4], bgv[4], bmv[4], pca0[4], pca1[4];
#pragma unroll
  for (int nt = 0; nt < 4; ++nt) {
    int col = nt * 16 + c15;
    bnv[nt] = bn[col]; bev[nt] = be[col]; bgv[nt] = bg[col]; bmv[nt] = bm[col];
  }
#pragma unroll
  for (int nt = 0; nt < 4; ++nt) {
    pca0[nt] = pcs[(2 * w + 0) * 64 + nt * 16 + c15];
    pca1[nt] = pcs[(2 * w + 1) * 64 + nt * 16 + c15];
  }

  // ================= phase A: phi_n, phi_e -> inter (overwrite NbrX) =========
  {
    short8 WnF[2][4], WeF[2][4];
#pragma unroll
    for (int ks = 0; ks < 2; ++ks)
#pragma unroll
      for (int nt = 0; nt < 4; ++nt) {
        int n = nt * 16 + c15, k0 = ks * 32 + g * 8;
        WnF[ks][nt] = *reinterpret_cast<const short8*>(Wt + 0 * 4096 + n * 64 + k0);
        WeF[ks][nt] = *reinterpret_cast<const short8*>(Wt + 1 * 4096 + n * 64 + k0);
      }
#pragma unroll
    for (int t = 0; t < 3; ++t) {
      int rbase = 48 * w + 16 * t;
      short8 aN0 = *reinterpret_cast<const short8*>(&NbrX[(rbase + c15) * 72 + g * 8]);
      short8 aN1 = *reinterpret_cast<const short8*>(&NbrX[(rbase + c15) * 72 + 32 + g * 8]);
      short8 aE0 = *reinterpret_cast<const short8*>(&NbrF[(rbase + c15) * 72 + g * 8]);
      short8 aE1 = *reinterpret_cast<const short8*>(&NbrF[(rbase + c15) * 72 + 32 + g * 8]);
      f32x4 P[4], E[4];
#pragma unroll
      for (int nt = 0; nt < 4; ++nt) {
        f32x4 z = {0.f, 0.f, 0.f, 0.f};
        P[nt] = MFMA_BF16(aN0, WnF[0][nt], z, 0, 0, 0);
        P[nt] = MFMA_BF16(aN1, WnF[1][nt], P[nt], 0, 0, 0);
        E[nt] = MFMA_BF16(aE0, WeF[0][nt], z, 0, 0, 0);
        E[nt] = MFMA_BF16(aE1, WeF[1][nt], E[nt], 0, 0, 0);
      }
      // inter = pc * (P+bn) * (E+be) -> bf16 into NbrX (wave-private rows)
#pragma unroll
      for (int nt = 0; nt < 4; ++nt)
#pragma unroll
        for (int r = 0; r < 4; ++r) {
          int grow = 16 * t + 4 * g + r;  // 0..47 within wave
          float pn = P[nt][r] + bnv[nt];
          float pe = E[nt][r] + bev[nt];
          float pcv = (grow < 24) ? pca0[nt] : pca1[nt];
          NbrX[(48 * w + grow) * 72 + nt * 16 + c15] = f2b(pcv * pn * pe);
        }
    }
  }
  lds_fence();
  __builtin_amdgcn_sched_barrier(0);

  // ================= phase B: gate/mag GEMMs + neighbor reduce ===============
  float as0[4] = {0.f, 0.f, 0.f, 0.f}, as1[4] = {0.f, 0.f, 0.f, 0.f};
  {
    short8 WgF[2][4], WmF[2][4];
#pragma unroll
    for (int ks = 0; ks < 2; ++ks)
#pragma unroll
      for (int nt = 0; nt < 4; ++nt) {
        int n = nt * 16 + c15, k0 = ks * 32 + g * 8;
        WgF[ks][nt] = *reinterpret_cast<const short8*>(Wt + 2 * 4096 + n * 64 + k0);
        WmF[ks][nt] = *reinterpret_cast<const short8*>(Wt + 3 * 4096 + n * 64 + k0);
      }
#pragma unroll
    for (int t = 0; t < 3; ++t) {
      int rbase = 48 * w + 16 * t;
      short8 aI0 = *reinterpret_cast<const short8*>(&NbrX[(rbase + c15) * 72 + g * 8]);
      short8 aI1 = *reinterpret_cast<const short8*>(&NbrX[(rbase + c15) * 72 + 32 + g * 8]);
      f32x4 G[4], S[4];
#pragma unroll
      for (int nt = 0; nt < 4; ++nt) {
        f32x4 z = {0.f, 0.f, 0.f, 0.f};
        G[nt] = MFMA_BF16(aI0, WgF[0][nt], z, 0, 0, 0);
        G[nt] = MFMA_BF16(aI1, WgF[1][nt], G[nt], 0, 0, 0);
        S[nt] = MFMA_BF16(aI0, WmF[0][nt], z, 0, 0, 0);
        S[nt] = MFMA_BF16(aI1, WmF[1][nt], S[nt], 0, 0, 0);
      }
#pragma unroll
      for (int nt = 0; nt < 4; ++nt)
#pragma unroll
        for (int r = 0; r < 4; ++r) {
          int grow = 16 * t + 4 * g + r;
          float gate = sigm(G[nt][r] + bgv[nt]);
          float mag = sftp(S[nt][r] + bmv[nt]);
          float o = gate * mag;
          as0[nt] += (grow < 24) ? o : 0.f;
          as1[nt] += (grow < 24) ? 0.f : o;
        }
    }
  }
  // cross-lane-group reduce (rows of an atom spread over lane groups) + h RMW
#pragma unroll
  for (int nt = 0; nt < 4; ++nt) {
    float v0 = as0[nt];
    v0 += __shfl_xor(v0, 16, 64); v0 += __shfl_xor(v0, 32, 64);
    float v1 = as1[nt];
    v1 += __shfl_xor(v1, 16, 64); v1 += __shfl_xor(v1, 32, 64);
    if (l < 16) {
      size_t o0 = (size_t)(atom0 + 2 * w) * 64 + nt * 16 + l;
      h[o0] += v0;
      h[o0 + 64] += v1;  // atom 2w+1
    }
  }
}

// ---------------------------------------------------------------- embed
__global__ __launch_bounds__(256) void k_embed(
    const float* __restrict__ af, const float* __restrict__ Wemb,
    const float* __restrict__ bemb, float* __restrict__ h, int nAtoms) {
  __shared__ float Ws[96 * 64];
  __shared__ float rows[4][96];
  int tid = threadIdx.x;
  for (int t = tid; t < 96 * 64; t += 256) {
    int r = t >> 6;
    Ws[t] = (r < RAWF) ? Wemb[t] : 0.f;
  }
  __syncthreads();
  int w = tid >> 6, j = tid & 63;
  float bj = bemb[j];
  int wg = (blockIdx.x << 2) + w, nw = gridDim.x << 2;
  for (int n = wg; n < nAtoms; n += nw) {
    const float* ar = af + (size_t)n * RAWF;
    rows[w][j] = ar[j];
    if (j < 32) rows[w][64 + j] = (64 + j < RAWF) ? ar[64 + j] : 0.f;
    lds_fence();
    float acc = bj;
#pragma unroll
    for (int kk = 0; kk < 24; ++kk) {
      float4 q = *reinterpret_cast<const float4*>(&rows[w][kk * 4]);
      const float* base = &Ws[(kk * 4) * 64 + j];
      acc += q.x * base[0] + q.y * base[64] + q.z * base[128] + q.w * base[192];
    }
    h[(size_t)n * 64 + j] = acc;
    lds_fence();
  }
}

// ---------------------------------------------------------------- LN + phi_c
__global__ __launch_bounds__(256) void k_ln_phic(
    const float* __restrict__ h, const float* __restrict__ lns,
    const float* __restrict__ lnb, const float* __restrict__ Wc,
    const float* __restrict__ bc, float* __restrict__ x, float* __restrict__ pc,
    int nAtoms) {
  __shared__ float Ws[64 * 64];
  __shared__ float rows[4][64];
  int tid = threadIdx.x;
  for (int t = tid; t < 1024; t += 256)
    reinterpret_cast<float4*>(Ws)[t] = reinterpret_cast<const float4*>(Wc)[t];
  __syncthreads();
  int w = tid >> 6, j = tid & 63;
  float sj = lns[j], bj = lnb[j], bcj = bc[j];
  int wg = (blockIdx.x << 2) + w, nw = gridDim.x << 2;
  for (int n = wg; n < nAtoms; n += nw) {
    float hv = h[(size_t)n * 64 + j];
    float mu = wsum64(hv) * (1.f / 64.f);
    float d = hv - mu;
    float var = wsum64(d * d) * (1.f / 64.f);
    float xv = d * rsqrtf(var + 1e-6f) * sj + bj;
    x[(size_t)n * 64 + j] = xv;
    rows[w][j] = xv;
    lds_fence();
    float acc = bcj;
#pragma unroll
    for (int kk = 0; kk < 16; ++kk) {
      float4 q = *reinterpret_cast<const float4*>(&rows[w][kk * 4]);
      const float* base = &Ws[(kk * 4) * 64 + j];
      acc += q.x * base[0] + q.y * base[64] + q.z * base[128] + q.w * base[192];
    }
    pc[(size_t)n * 64 + j] = acc;
    lds_fence();
  }
}

// ---------------------------------------------------------------- readout
__global__ __launch_bounds__(256) void k_readout(
    const float* __restrict__ h, const float* __restrict__ Wr1,
    const float* __restrict__ br1, const float* __restrict__ Wr2,
    const float* __restrict__ br2, const float* __restrict__ Wr3,
    const float* __restrict__ br3, float* __restrict__ partials, int nAtoms) {
  __shared__ float W1[64 * 128];
  __shared__ float W2[128 * 64];
  __shared__ float w3s[64];
  __shared__ float rowbuf[4][128];
  __shared__ float wsum[4];
  int tid = threadIdx.x;
  for (int t = tid; t < 2048; t += 256) {
    reinterpret_cast<float4*>(W1)[t] = reinterpret_cast<const float4*>(Wr1)[t];
    reinterpret_cast<float4*>(W2)[t] = reinterpret_cast<const float4*>(Wr2)[t];
  }
  if (tid < 64) w3s[tid] = Wr3[tid];
  __syncthreads();
  int w = tid >> 6, j = tid & 63;
  float b1a = br1[j], b1b = br1[64 + j], b2 = br2[j];
  float w3 = w3s[j], br3v = br3[0];
  float lsum = 0.f;
  int wg = (blockIdx.x << 2) + w, nw = gridDim.x << 2;
  for (int n = wg; n < nAtoms; n += nw) {
    lds_fence();
    rowbuf[w][j] = h[(size_t)n * 64 + j];
    lds_fence();
    float a0 = b1a, a1 = b1b;
#pragma unroll
    for (int kk = 0; kk < 16; ++kk) {
      float4 q = *reinterpret_cast<const float4*>(&rowbuf[w][kk * 4]);
      const float* base = &W1[(kk * 4) * 128 + j];
      a0 += q.x * base[0] + q.y * base[128] + q.z * base[256] + q.w * base[384];
      a1 += q.x * base[64] + q.y * base[192] + q.z * base[320] + q.w * base[448];
    }
    a0 = sftp(a0);
    a1 = sftp(a1);
    lds_fence();
    rowbuf[w][j] = a0;
    rowbuf[w][64 + j] = a1;
    lds_fence();
    float a2 = b2;
#pragma unroll
    for (int kk = 0; kk < 32; ++kk) {
      float4 q = *reinterpret_cast<const float4*>(&rowbuf[w][kk * 4]);
      const float* base = &W2[(kk * 4) * 64 + j];
      a2 += q.x * base[0] + q.y * base[64] + q.z * base[128] + q.w * base[192];
    }
    a2 = sftp(a2);
    float site = wsum64(a2 * w3) + br3v;
    if (j == 0) lsum += site;
  }
  if (j == 0) wsum[w] = lsum;
  __syncthreads();
  if (tid == 0)
    partials[blockIdx.x] = wsum[0] + wsum[1] + wsum[2] + wsum[3];
}

__global__ __launch_bounds__(256) void k_final(const float* __restrict__ partials,
                                               int nparts, float* __restrict__ out,
                                               float invN) {
  __shared__ float s[256];
  float v = 0.f;
  for (int t = threadIdx.x; t < nparts; t += 256) v += partials[t];
  s[threadIdx.x] = v;
  __syncthreads();
  for (int off = 128; off > 0; off >>= 1) {
    if (threadIdx.x < off) s[threadIdx.x] += s[threadIdx.x + off];
    __syncthreads();
  }
  if (threadIdx.x == 0) out[0] = s[0] * invN;
}

// ---------------------------------------------------------------- launch
extern "C" void kernel_launch(void* const* d_in, const int* in_sizes, int n_in,
                              void* d_out, int out_size, void* d_ws, size_t ws_size,
                              hipStream_t stream) {
  const float* af   = (const float*)d_in[0];
  const float* nbrf = (const float*)d_in[1];
  const int*   idx  = (const int*)d_in[2];
  const float* Wemb = (const float*)d_in[3];
  const float* bemb = (const float*)d_in[4];
  const float* ln_s = (const float*)d_in[5];
  const float* ln_b = (const float*)d_in[6];
  const float* Wc   = (const float*)d_in[7];
  const float* bc   = (const float*)d_in[8];
  const float* Wn   = (const float*)d_in[9];
  const float* bn   = (const float*)d_in[10];
  const float* We   = (const float*)d_in[11];
  const float* be   = (const float*)d_in[12];
  const float* Wg   = (const float*)d_in[13];
  const float* bg   = (const float*)d_in[14];
  const float* Wm   = (const float*)d_in[15];
  const float* bm   = (const float*)d_in[16];
  const float* Wr1  = (const float*)d_in[17];
  const float* br1  = (const float*)d_in[18];
  const float* Wr2  = (const float*)d_in[19];
  const float* br2  = (const float*)d_in[20];
  const float* Wr3  = (const float*)d_in[21];
  const float* br3  = (const float*)d_in[22];

  int N = in_sizes[0] / RAWF;  // 50000
  float* ws = (float*)d_ws;
  size_t nc = (size_t)N * CF;
  float* h   = ws;
  float* x   = ws + nc;
  float* pcb = ws + 2 * nc;
  float* partials = ws + 3 * nc;                 // 512 floats
  ushort* Wt = (ushort*)(ws + 3 * nc + 1024);    // [3][4][64][64] bf16
  const int RO_GRID = 512;

  k_prep<<<12, 256, 0, stream>>>(Wn, We, Wg, Wm, Wt);
  k_embed<<<1024, 256, 0, stream>>>(af, Wemb, bemb, h, N);
  for (int i = 0; i < 3; ++i) {
    k_ln_phic<<<1024, 256, 0, stream>>>(h, ln_s + i * 64, ln_b + i * 64,
                                        Wc + i * 4096, bc + i * 64, x, pcb, N);
    k_conv_mfma<<<N / 8, 256, 0, stream>>>(x, pcb, nbrf, idx,
                                           Wt + (size_t)i * 4 * 4096,
                                           bn + i * 64, be + i * 64,
                                           bg + i * 64, bm + i * 64, h, N);
  }
  k_readout<<<RO_GRID, 256, 0, stream>>>(h, Wr1, br1, Wr2, br2, Wr3, br3,
                                         partials, N);
  k_final<<<1, 256, 0, stream>>>(partials, RO_GRID, (float*)d_out, 1.f / N);
}

// Round 3
// 866.215 us; speedup vs baseline: 30.9931x; 1.0543x over previous
//
#include <hip/hip_runtime.h>
#include <math.h>

#define RAWF 92
#define CF 64
#define NBRF 41
#define MN 24
#define HD 128

typedef short short8 __attribute__((ext_vector_type(8)));
typedef float f32x4 __attribute__((ext_vector_type(4)));
#define MFMA_BF16 __builtin_amdgcn_mfma_f32_16x16x32_bf16

__device__ __forceinline__ void lds_fence() {
  asm volatile("s_waitcnt lgkmcnt(0)" ::: "memory");
  __builtin_amdgcn_wave_barrier();
}

__device__ __forceinline__ float wsum64(float v) {
#pragma unroll
  for (int m = 32; m >= 1; m >>= 1) v += __shfl_xor(v, m, 64);
  return v;
}

__device__ __forceinline__ float sigm(float x) { return 1.f / (1.f + __expf(-x)); }
__device__ __forceinline__ float sftp(float x) { return x > 20.f ? x : __logf(1.f + __expf(x)); }

__device__ __forceinline__ ushort f2b(float f) {  // RNE float->bf16
  unsigned u = __float_as_uint(f);
  return (ushort)((u + 0x7FFFu + ((u >> 16) & 1u)) >> 16);
}

// ------------------------------------------------ weight transpose+cast (once)
// Wt layout: [layer][mat(n,e,g,m)][n=64][k=64] bf16, We K-padded with zeros
__global__ __launch_bounds__(256) void k_prep(
    const float* __restrict__ Wn, const float* __restrict__ We,
    const float* __restrict__ Wg, const float* __restrict__ Wm,
    ushort* __restrict__ Wt) {
  int bid = blockIdx.x, layer = bid >> 2, mat = bid & 3;
  const float* src;
  int Krows = 64;
  if (mat == 0) src = Wn + layer * 4096;
  else if (mat == 1) { src = We + layer * NBRF * 64; Krows = NBRF; }
  else if (mat == 2) src = Wg + layer * 4096;
  else src = Wm + layer * 4096;
  ushort* dst = Wt + bid * 4096;
  for (int i = threadIdx.x; i < 4096; i += 256) {
    int n = i >> 6, k = i & 63;
    float v = (k < Krows) ? src[k * 64 + n] : 0.f;
    dst[n * 64 + k] = f2b(v);
  }
}

// ------------------------------------------------ nbr_fea f32 -> bf16 [rows][48]
__global__ __launch_bounds__(256) void k_prep_nbrf(
    const float* __restrict__ nbrf, ushort* __restrict__ nbf, unsigned nrows) {
  unsigned total4 = nrows * NBRF / 4;  // 12.3M float4s
  unsigned stride = gridDim.x * 256;
  for (unsigned i = blockIdx.x * 256 + threadIdx.x; i < total4; i += stride) {
    float4 v = reinterpret_cast<const float4*>(nbrf)[i];
    unsigned e = i * 4;
    float vv[4] = {v.x, v.y, v.z, v.w};
#pragma unroll
    for (int k = 0; k < 4; ++k) {
      unsigned ek = e + k;
      unsigned row = (unsigned)(((unsigned long long)ek * 104755300ull) >> 32);
      unsigned col = ek - row * 41u;
      nbf[(size_t)row * 48 + col] = f2b(vv[k]);
    }
  }
  // zero-fill pad cols 41..47
  unsigned total7 = nrows * 7;
  for (unsigned j = blockIdx.x * 256 + threadIdx.x; j < total7; j += stride) {
    unsigned row = (unsigned)(((unsigned long long)j * 613566757ull) >> 32);
    unsigned col = 41 + (j - row * 7u);
    nbf[(size_t)row * 48 + col] = 0;
  }
}

// ------------------------------------------------ conv v2: direct-global A-frags
// block = 8 atoms; wave w owns global rows [atom0*24+48w, +48) = atoms 2w,2w+1
__global__ __launch_bounds__(256) void k_conv_mfma2(
    const ushort* __restrict__ xbf, const float* __restrict__ pcg,
    const ushort* __restrict__ nbf, const int* __restrict__ idx,
    const ushort* __restrict__ Wt, const float* __restrict__ bn,
    const float* __restrict__ be, const float* __restrict__ bg,
    const float* __restrict__ bm, float* __restrict__ h) {
  __shared__ ushort Inter[192 * 64];  // XOR-swizzled, wave-private 48-row slices

  int tid = threadIdx.x;
  int w = tid >> 6, l = tid & 63, g = l >> 4, c15 = l & 15;
  int atom0 = blockIdx.x * 8;
  size_t rowg0 = (size_t)atom0 * MN + 48 * w;  // this wave's first global row
  int myidx = (l < 48) ? idx[rowg0 + l] : 0;

  float bnv[4], bev[4], bgv[4], bmv[4], pca0[4], pca1[4];
#pragma unroll
  for (int nt = 0; nt < 4; ++nt) {
    int col = nt * 16 + c15;
    bnv[nt] = bn[col]; bev[nt] = be[col]; bgv[nt] = bg[col]; bmv[nt] = bm[col];
    pca0[nt] = pcg[(size_t)(atom0 + 2 * w) * 64 + col];
    pca1[nt] = pcg[(size_t)(atom0 + 2 * w + 1) * 64 + col];
  }

  ushort* InterW = Inter + 48 * 64 * w;
  int swzr = (c15 & 7) << 3;  // read-side swizzle (ushort units)

  // ================= phase A: phi_n, phi_e -> inter ==========================
  {
    short8 WnF[2][4], WeF[2][4];
#pragma unroll
    for (int ks = 0; ks < 2; ++ks)
#pragma unroll
      for (int nt = 0; nt < 4; ++nt) {
        int n = nt * 16 + c15, k0 = ks * 32 + g * 8;
        WnF[ks][nt] = *reinterpret_cast<const short8*>(Wt + 0 * 4096 + n * 64 + k0);
        WeF[ks][nt] = *reinterpret_cast<const short8*>(Wt + 1 * 4096 + n * 64 + k0);
      }
    short8 z8 = {0, 0, 0, 0, 0, 0, 0, 0};
#pragma unroll
    for (int t = 0; t < 3; ++t) {
      int rl = 16 * t + c15;  // row within wave
      int nb = __shfl(myidx, rl, 64);
      const ushort* xr = xbf + (size_t)nb * 64;
      short8 aN0 = *reinterpret_cast<const short8*>(xr + g * 8);
      short8 aN1 = *reinterpret_cast<const short8*>(xr + 32 + g * 8);
      const ushort* er = nbf + (rowg0 + rl) * 48;
      short8 aE0 = *reinterpret_cast<const short8*>(er + g * 8);
      short8 aE1 = (g < 2) ? *reinterpret_cast<const short8*>(er + 32 + g * 8) : z8;
      f32x4 P[4], E[4];
#pragma unroll
      for (int nt = 0; nt < 4; ++nt) {
        f32x4 z = {0.f, 0.f, 0.f, 0.f};
        P[nt] = MFMA_BF16(aN0, WnF[0][nt], z, 0, 0, 0);
        P[nt] = MFMA_BF16(aN1, WnF[1][nt], P[nt], 0, 0, 0);
        E[nt] = MFMA_BF16(aE0, WeF[0][nt], z, 0, 0, 0);
        E[nt] = MFMA_BF16(aE1, WeF[1][nt], E[nt], 0, 0, 0);
      }
#pragma unroll
      for (int nt = 0; nt < 4; ++nt)
#pragma unroll
        for (int r = 0; r < 4; ++r) {
          int grow = 16 * t + 4 * g + r;  // 0..47 within wave
          float pn = P[nt][r] + bnv[nt];
          float pe = E[nt][r] + bev[nt];
          float pcv = (grow < 24) ? pca0[nt] : pca1[nt];
          int col = nt * 16 + c15;
          InterW[grow * 64 + (col ^ (((4 * g + r) & 7) << 3))] = f2b(pcv * pn * pe);
        }
    }
  }
  lds_fence();
  __builtin_amdgcn_sched_barrier(0);

  // ================= phase B: gate/mag GEMMs + neighbor reduce ===============
  float as0[4] = {0.f, 0.f, 0.f, 0.f}, as1[4] = {0.f, 0.f, 0.f, 0.f};
  {
    short8 WgF[2][4], WmF[2][4];
#pragma unroll
    for (int ks = 0; ks < 2; ++ks)
#pragma unroll
      for (int nt = 0; nt < 4; ++nt) {
        int n = nt * 16 + c15, k0 = ks * 32 + g * 8;
        WgF[ks][nt] = *reinterpret_cast<const short8*>(Wt + 2 * 4096 + n * 64 + k0);
        WmF[ks][nt] = *reinterpret_cast<const short8*>(Wt + 3 * 4096 + n * 64 + k0);
      }
#pragma unroll
    for (int t = 0; t < 3; ++t) {
      const ushort* rowp = InterW + (16 * t + c15) * 64;
      short8 aI0 = *reinterpret_cast<const short8*>(rowp + ((g * 8) ^ swzr));
      short8 aI1 = *reinterpret_cast<const short8*>(rowp + ((32 + g * 8) ^ swzr));
      f32x4 G[4], S[4];
#pragma unroll
      for (int nt = 0; nt < 4; ++nt) {
        f32x4 z = {0.f, 0.f, 0.f, 0.f};
        G[nt] = MFMA_BF16(aI0, WgF[0][nt], z, 0, 0, 0);
        G[nt] = MFMA_BF16(aI1, WgF[1][nt], G[nt], 0, 0, 0);
        S[nt] = MFMA_BF16(aI0, WmF[0][nt], z, 0, 0, 0);
        S[nt] = MFMA_BF16(aI1, WmF[1][nt], S[nt], 0, 0, 0);
      }
#pragma unroll
      for (int nt = 0; nt < 4; ++nt)
#pragma unroll
        for (int r = 0; r < 4; ++r) {
          int grow = 16 * t + 4 * g + r;
          float gate = sigm(G[nt][r] + bgv[nt]);
          float mag = sftp(S[nt][r] + bmv[nt]);
          float o = gate * mag;
          as0[nt] += (grow < 24) ? o : 0.f;
          as1[nt] += (grow < 24) ? 0.f : o;
        }
    }
  }
#pragma unroll
  for (int nt = 0; nt < 4; ++nt) {
    float v0 = as0[nt];
    v0 += __shfl_xor(v0, 16, 64); v0 += __shfl_xor(v0, 32, 64);
    float v1 = as1[nt];
    v1 += __shfl_xor(v1, 16, 64); v1 += __shfl_xor(v1, 32, 64);
    if (l < 16) {
      size_t o0 = (size_t)(atom0 + 2 * w) * 64 + nt * 16 + l;
      h[o0] += v0;
      h[o0 + 64] += v1;
    }
  }
}

// ------------------------------------------------ conv v1 (fallback, proven)
__global__ __launch_bounds__(256) void k_conv_mfma(
    const float* __restrict__ x, const float* __restrict__ pcg,
    const float* __restrict__ nbrf, const int* __restrict__ idx,
    const ushort* __restrict__ Wt,
    const float* __restrict__ bn, const float* __restrict__ be,
    const float* __restrict__ bg, const float* __restrict__ bm,
    float* __restrict__ h, int nAtoms) {
  __shared__ ushort NbrX[192 * 72];
  __shared__ ushort NbrF[192 * 72];
  __shared__ float pcs[8 * 64];

  int tid = threadIdx.x;
  int w = tid >> 6, l = tid & 63, g = l >> 4, c15 = l & 15;
  int atom0 = blockIdx.x * 8;
  size_t rowg0 = (size_t)atom0 * MN;

  int myidx = 0;
  if (l < 48) myidx = idx[rowg0 + 48 * w + l];
  {
    float2 xv[24];
#pragma unroll
    for (int i = 0; i < 24; ++i) {
      int nb = __shfl(myidx, 2 * i + (l >> 5), 64);
      xv[i] = *reinterpret_cast<const float2*>(x + (size_t)nb * 64 + 2 * (l & 31));
    }
    unsigned* nbx32 = reinterpret_cast<unsigned*>(NbrX);
#pragma unroll
    for (int i = 0; i < 24; ++i) {
      int lr = 48 * w + 2 * i + (l >> 5);
      unsigned p = (unsigned)f2b(xv[i].x) | ((unsigned)f2b(xv[i].y) << 16);
      nbx32[lr * 36 + (l & 31)] = p;
    }
  }
  {
    float fv[48];
#pragma unroll
    for (int i = 0; i < 48; ++i) {
      int lr = 48 * w + i;
      fv[i] = (l < NBRF) ? nbrf[(rowg0 + lr) * NBRF + l] : 0.f;
    }
#pragma unroll
    for (int i = 0; i < 48; ++i) {
      int lr = 48 * w + i;
      NbrF[lr * 72 + l] = f2b(fv[i]);
    }
  }
#pragma unroll
  for (int rr = 0; rr < 2; ++rr) {
    int la = 2 * w + rr;
    pcs[la * 64 + l] = pcg[(size_t)(atom0 + la) * 64 + l];
  }
  float bnv[4], bev[4], bgv[4], bmv[4], pca0[4], pca1[4];
#pragma unroll
  for (int nt = 0; nt < 4; ++nt) {
    int col = nt * 16 + c15;
    bnv[nt] = bn[col]; bev[nt] = be[col]; bgv[nt] = bg[col]; bmv[nt] = bm[col];
  }
#pragma unroll
  for (int nt = 0; nt < 4; ++nt) {
    pca0[nt] = pcs[(2 * w + 0) * 64 + nt * 16 + c15];
    pca1[nt] = pcs[(2 * w + 1) * 64 + nt * 16 + c15];
  }
  {
    short8 WnF[2][4], WeF[2][4];
#pragma unroll
    for (int ks = 0; ks < 2; ++ks)
#pragma unroll
      for (int nt = 0; nt < 4; ++nt) {
        int n = nt * 16 + c15, k0 = ks * 32 + g * 8;
        WnF[ks][nt] = *reinterpret_cast<const short8*>(Wt + 0 * 4096 + n * 64 + k0);
        WeF[ks][nt] = *reinterpret_cast<const short8*>(Wt + 1 * 4096 + n * 64 + k0);
      }
#pragma unroll
    for (int t = 0; t < 3; ++t) {
      int rbase = 48 * w + 16 * t;
      short8 aN0 = *reinterpret_cast<const short8*>(&NbrX[(rbase + c15) * 72 + g * 8]);
      short8 aN1 = *reinterpret_cast<const short8*>(&NbrX[(rbase + c15) * 72 + 32 + g * 8]);
      short8 aE0 = *reinterpret_cast<const short8*>(&NbrF[(rbase + c15) * 72 + g * 8]);
      short8 aE1 = *reinterpret_cast<const short8*>(&NbrF[(rbase + c15) * 72 + 32 + g * 8]);
      f32x4 P[4], E[4];
#pragma unroll
      for (int nt = 0; nt < 4; ++nt) {
        f32x4 z = {0.f, 0.f, 0.f, 0.f};
        P[nt] = MFMA_BF16(aN0, WnF[0][nt], z, 0, 0, 0);
        P[nt] = MFMA_BF16(aN1, WnF[1][nt], P[nt], 0, 0, 0);
        E[nt] = MFMA_BF16(aE0, WeF[0][nt], z, 0, 0, 0);
        E[nt] = MFMA_BF16(aE1, WeF[1][nt], E[nt], 0, 0, 0);
      }
#pragma unroll
      for (int nt = 0; nt < 4; ++nt)
#pragma unroll
        for (int r = 0; r < 4; ++r) {
          int grow = 16 * t + 4 * g + r;
          float pn = P[nt][r] + bnv[nt];
          float pe = E[nt][r] + bev[nt];
          float pcv = (grow < 24) ? pca0[nt] : pca1[nt];
          NbrX[(48 * w + grow) * 72 + nt * 16 + c15] = f2b(pcv * pn * pe);
        }
    }
  }
  lds_fence();
  __builtin_amdgcn_sched_barrier(0);
  float as0[4] = {0.f, 0.f, 0.f, 0.f}, as1[4] = {0.f, 0.f, 0.f, 0.f};
  {
    short8 WgF[2][4], WmF[2][4];
#pragma unroll
    for (int ks = 0; ks < 2; ++ks)
#pragma unroll
      for (int nt = 0; nt < 4; ++nt) {
        int n = nt * 16 + c15, k0 = ks * 32 + g * 8;
        WgF[ks][nt] = *reinterpret_cast<const short8*>(Wt + 2 * 4096 + n * 64 + k0);
        WmF[ks][nt] = *reinterpret_cast<const short8*>(Wt + 3 * 4096 + n * 64 + k0);
      }
#pragma unroll
    for (int t = 0; t < 3; ++t) {
      int rbase = 48 * w + 16 * t;
      short8 aI0 = *reinterpret_cast<const short8*>(&NbrX[(rbase + c15) * 72 + g * 8]);
      short8 aI1 = *reinterpret_cast<const short8*>(&NbrX[(rbase + c15) * 72 + 32 + g * 8]);
      f32x4 G[4], S[4];
#pragma unroll
      for (int nt = 0; nt < 4; ++nt) {
        f32x4 z = {0.f, 0.f, 0.f, 0.f};
        G[nt] = MFMA_BF16(aI0, WgF[0][nt], z, 0, 0, 0);
        G[nt] = MFMA_BF16(aI1, WgF[1][nt], G[nt], 0, 0, 0);
        S[nt] = MFMA_BF16(aI0, WmF[0][nt], z, 0, 0, 0);
        S[nt] = MFMA_BF16(aI1, WmF[1][nt], S[nt], 0, 0, 0);
      }
#pragma unroll
      for (int nt = 0; nt < 4; ++nt)
#pragma unroll
        for (int r = 0; r < 4; ++r) {
          int grow = 16 * t + 4 * g + r;
          float gate = sigm(G[nt][r] + bgv[nt]);
          float mag = sftp(S[nt][r] + bmv[nt]);
          float o = gate * mag;
          as0[nt] += (grow < 24) ? o : 0.f;
          as1[nt] += (grow < 24) ? 0.f : o;
        }
    }
  }
#pragma unroll
  for (int nt = 0; nt < 4; ++nt) {
    float v0 = as0[nt];
    v0 += __shfl_xor(v0, 16, 64); v0 += __shfl_xor(v0, 32, 64);
    float v1 = as1[nt];
    v1 += __shfl_xor(v1, 16, 64); v1 += __shfl_xor(v1, 32, 64);
    if (l < 16) {
      size_t o0 = (size_t)(atom0 + 2 * w) * 64 + nt * 16 + l;
      h[o0] += v0;
      h[o0 + 64] += v1;
    }
  }
}

// ---------------------------------------------------------------- embed
__global__ __launch_bounds__(256) void k_embed(
    const float* __restrict__ af, const float* __restrict__ Wemb,
    const float* __restrict__ bemb, float* __restrict__ h, int nAtoms) {
  __shared__ float Ws[96 * 64];
  __shared__ float rows[4][96];
  int tid = threadIdx.x;
  for (int t = tid; t < 96 * 64; t += 256) {
    int r = t >> 6;
    Ws[t] = (r < RAWF) ? Wemb[t] : 0.f;
  }
  __syncthreads();
  int w = tid >> 6, j = tid & 63;
  float bj = bemb[j];
  int wg = (blockIdx.x << 2) + w, nw = gridDim.x << 2;
  for (int n = wg; n < nAtoms; n += nw) {
    const float* ar = af + (size_t)n * RAWF;
    rows[w][j] = ar[j];
    if (j < 32) rows[w][64 + j] = (64 + j < RAWF) ? ar[64 + j] : 0.f;
    lds_fence();
    float acc = bj;
#pragma unroll
    for (int kk = 0; kk < 24; ++kk) {
      float4 q = *reinterpret_cast<const float4*>(&rows[w][kk * 4]);
      const float* base = &Ws[(kk * 4) * 64 + j];
      acc += q.x * base[0] + q.y * base[64] + q.z * base[128] + q.w * base[192];
    }
    h[(size_t)n * 64 + j] = acc;
    lds_fence();
  }
}

// ---------------------------------------------------------------- LN + phi_c
__global__ __launch_bounds__(256) void k_ln_phic(
    const float* __restrict__ h, const float* __restrict__ lns,
    const float* __restrict__ lnb, const float* __restrict__ Wc,
    const float* __restrict__ bc, float* __restrict__ x, ushort* __restrict__ xbf,
    float* __restrict__ pc, int nAtoms) {
  __shared__ float Ws[64 * 64];
  __shared__ float rows[4][64];
  int tid = threadIdx.x;
  for (int t = tid; t < 1024; t += 256)
    reinterpret_cast<float4*>(Ws)[t] = reinterpret_cast<const float4*>(Wc)[t];
  __syncthreads();
  int w = tid >> 6, j = tid & 63;
  float sj = lns[j], bj = lnb[j], bcj = bc[j];
  int wg = (blockIdx.x << 2) + w, nw = gridDim.x << 2;
  for (int n = wg; n < nAtoms; n += nw) {
    float hv = h[(size_t)n * 64 + j];
    float mu = wsum64(hv) * (1.f / 64.f);
    float d = hv - mu;
    float var = wsum64(d * d) * (1.f / 64.f);
    float xv = d * rsqrtf(var + 1e-6f) * sj + bj;
    x[(size_t)n * 64 + j] = xv;
    if (xbf) xbf[(size_t)n * 64 + j] = f2b(xv);
    rows[w][j] = xv;
    lds_fence();
    float acc = bcj;
#pragma unroll
    for (int kk = 0; kk < 16; ++kk) {
      float4 q = *reinterpret_cast<const float4*>(&rows[w][kk * 4]);
      const float* base = &Ws[(kk * 4) * 64 + j];
      acc += q.x * base[0] + q.y * base[64] + q.z * base[128] + q.w * base[192];
    }
    pc[(size_t)n * 64 + j] = acc;
    lds_fence();
  }
}

// ---------------------------------------------------------------- readout
__global__ __launch_bounds__(256) void k_readout(
    const float* __restrict__ h, const float* __restrict__ Wr1,
    const float* __restrict__ br1, const float* __restrict__ Wr2,
    const float* __restrict__ br2, const float* __restrict__ Wr3,
    const float* __restrict__ br3, float* __restrict__ partials, int nAtoms) {
  __shared__ float W1[64 * 128];
  __shared__ float W2[128 * 64];
  __shared__ float w3s[64];
  __shared__ float rowbuf[4][128];
  __shared__ float wsum[4];
  int tid = threadIdx.x;
  for (int t = tid; t < 2048; t += 256) {
    reinterpret_cast<float4*>(W1)[t] = reinterpret_cast<const float4*>(Wr1)[t];
    reinterpret_cast<float4*>(W2)[t] = reinterpret_cast<const float4*>(Wr2)[t];
  }
  if (tid < 64) w3s[tid] = Wr3[tid];
  __syncthreads();
  int w = tid >> 6, j = tid & 63;
  float b1a = br1[j], b1b = br1[64 + j], b2 = br2[j];
  float w3 = w3s[j], br3v = br3[0];
  float lsum = 0.f;
  int wg = (blockIdx.x << 2) + w, nw = gridDim.x << 2;
  for (int n = wg; n < nAtoms; n += nw) {
    lds_fence();
    rowbuf[w][j] = h[(size_t)n * 64 + j];
    lds_fence();
    float a0 = b1a, a1 = b1b;
#pragma unroll
    for (int kk = 0; kk < 16; ++kk) {
      float4 q = *reinterpret_cast<const float4*>(&rowbuf[w][kk * 4]);
      const float* base = &W1[(kk * 4) * 128 + j];
      a0 += q.x * base[0] + q.y * base[128] + q.z * base[256] + q.w * base[384];
      a1 += q.x * base[64] + q.y * base[192] + q.z * base[320] + q.w * base[448];
    }
    a0 = sftp(a0);
    a1 = sftp(a1);
    lds_fence();
    rowbuf[w][j] = a0;
    rowbuf[w][64 + j] = a1;
    lds_fence();
    float a2 = b2;
#pragma unroll
    for (int kk = 0; kk < 32; ++kk) {
      float4 q = *reinterpret_cast<const float4*>(&rowbuf[w][kk * 4]);
      const float* base = &W2[(kk * 4) * 64 + j];
      a2 += q.x * base[0] + q.y * base[64] + q.z * base[128] + q.w * base[192];
    }
    a2 = sftp(a2);
    float site = wsum64(a2 * w3) + br3v;
    if (j == 0) lsum += site;
  }
  if (j == 0) wsum[w] = lsum;
  __syncthreads();
  if (tid == 0)
    partials[blockIdx.x] = wsum[0] + wsum[1] + wsum[2] + wsum[3];
}

__global__ __launch_bounds__(256) void k_final(const float* __restrict__ partials,
                                               int nparts, float* __restrict__ out,
                                               float invN) {
  __shared__ float s[256];
  float v = 0.f;
  for (int t = threadIdx.x; t < nparts; t += 256) v += partials[t];
  s[threadIdx.x] = v;
  __syncthreads();
  for (int off = 128; off > 0; off >>= 1) {
    if (threadIdx.x < off) s[threadIdx.x] += s[threadIdx.x + off];
    __syncthreads();
  }
  if (threadIdx.x == 0) out[0] = s[0] * invN;
}

// ---------------------------------------------------------------- launch
extern "C" void kernel_launch(void* const* d_in, const int* in_sizes, int n_in,
                              void* d_out, int out_size, void* d_ws, size_t ws_size,
                              hipStream_t stream) {
  const float* af   = (const float*)d_in[0];
  const float* nbrf = (const float*)d_in[1];
  const int*   idx  = (const int*)d_in[2];
  const float* Wemb = (const float*)d_in[3];
  const float* bemb = (const float*)d_in[4];
  const float* ln_s = (const float*)d_in[5];
  const float* ln_b = (const float*)d_in[6];
  const float* Wc   = (const float*)d_in[7];
  const float* bc   = (const float*)d_in[8];
  const float* Wn   = (const float*)d_in[9];
  const float* bn   = (const float*)d_in[10];
  const float* We   = (const float*)d_in[11];
  const float* be   = (const float*)d_in[12];
  const float* Wg   = (const float*)d_in[13];
  const float* bg   = (const float*)d_in[14];
  const float* Wm   = (const float*)d_in[15];
  const float* bm   = (const float*)d_in[16];
  const float* Wr1  = (const float*)d_in[17];
  const float* br1  = (const float*)d_in[18];
  const float* Wr2  = (const float*)d_in[19];
  const float* br2  = (const float*)d_in[20];
  const float* Wr3  = (const float*)d_in[21];
  const float* br3  = (const float*)d_in[22];

  int N = in_sizes[0] / RAWF;  // 50000
  size_t rows = (size_t)N * MN;
  float* ws = (float*)d_ws;
  size_t nc = (size_t)N * CF;
  float* h   = ws;
  float* pcb = ws + nc;
  float* xf  = ws + 2 * nc;
  float* partials = ws + 3 * nc;                 // 1024 floats
  ushort* Wt  = (ushort*)(partials + 1024);      // 12*4096 bf16
  ushort* xbf = Wt + 12 * 4096;                  // nc bf16
  ushort* nbf = xbf + nc;                        // rows*48 bf16
  size_t need = (size_t)((char*)(nbf + rows * 48) - (char*)d_ws);
  bool newpath = ws_size >= need;
  const int RO_GRID = 512;

  k_prep<<<12, 256, 0, stream>>>(Wn, We, Wg, Wm, Wt);
  if (newpath)
    k_prep_nbrf<<<2048, 256, 0, stream>>>(nbrf, nbf, (unsigned)(rows));
  k_embed<<<1024, 256, 0, stream>>>(af, Wemb, bemb, h, N);
  for (int i = 0; i < 3; ++i) {
    k_ln_phic<<<1024, 256, 0, stream>>>(h, ln_s + i * 64, ln_b + i * 64,
                                        Wc + i * 4096, bc + i * 64, xf,
                                        newpath ? xbf : (ushort*)nullptr, pcb, N);
    if (newpath)
      k_conv_mfma2<<<N / 8, 256, 0, stream>>>(xbf, pcb, nbf, idx,
                                              Wt + (size_t)i * 4 * 4096,
                                              bn + i * 64, be + i * 64,
                                              bg + i * 64, bm + i * 64, h);
    else
      k_conv_mfma<<<N / 8, 256, 0, stream>>>(xf, pcb, nbrf, idx,
                                             Wt + (size_t)i * 4 * 4096,
                                             bn + i * 64, be + i * 64,
                                             bg + i * 64, bm + i * 64, h, N);
  }
  k_readout<<<RO_GRID, 256, 0, stream>>>(h, Wr1, br1, Wr2, br2, Wr3, br3,
                                         partials, N);
  k_final<<<1, 256, 0, stream>>>(partials, RO_GRID, (float*)d_out, 1.f / N);
}